// Round 3
// baseline (442.026 us; speedup 1.0000x reference)
//
#include <hip/hip_runtime.h>

typedef unsigned short u16;
typedef unsigned int   u32;
typedef unsigned long long u64;

typedef __bf16 bf16x8 __attribute__((ext_vector_type(8)));
typedef float  f32x4  __attribute__((ext_vector_type(4)));
typedef u16    u16x4  __attribute__((ext_vector_type(4)));
typedef u16    u16x8  __attribute__((ext_vector_type(8)));

#define IN_F   4096
#define OUT_F  11008
#define TOKENS 4096

#define BM 256
#define BN 128
#define BK 32
#define MT (TOKENS / BM)   // 16
#define NT (OUT_F / BN)    // 86
#define KTILES (IN_F / BK) // 128

// f32 -> bf16 round-to-nearest-even (exact for integers 0..255)
__device__ __forceinline__ u16 f2bf(float f) {
    u32 u = __float_as_uint(f);
    return (u16)((u + 0x7FFFu + ((u >> 16) & 1u)) >> 16);
}

// direct global->LDS async copy, 16B per lane; LDS dest = wave-uniform base + lane*16
#define GLOAD_LDS16(g, l)                                                        \
    __builtin_amdgcn_global_load_lds(                                            \
        (const __attribute__((address_space(1))) u32*)(u64)(g),                  \
        (__attribute__((address_space(3))) u32*)(u64)(l), 16, 0, 0)

#define BAR() __builtin_amdgcn_s_barrier()
#define VM(N) asm volatile("s_waitcnt vmcnt(" #N ")" ::: "memory")

// ---------------- prep_x: f32 -> bf16, plus per-row f32 sum ----------------
__global__ __launch_bounds__(256) void prep_x_kernel(
    const float* __restrict__ x, u16* __restrict__ xb, float* __restrict__ rowsum) {
    const int row = blockIdx.x;
    const int tid = threadIdx.x;
    const float4* xr = reinterpret_cast<const float4*>(x + (size_t)row * IN_F);
    u16x4* xo = reinterpret_cast<u16x4*>(xb + (size_t)row * IN_F);
    float s = 0.f;
#pragma unroll
    for (int i = 0; i < 4; ++i) {
        float4 v = xr[tid * 4 + i];
        s += v.x + v.y + v.z + v.w;
        u16x4 o;
        o[0] = f2bf(v.x); o[1] = f2bf(v.y); o[2] = f2bf(v.z); o[3] = f2bf(v.w);
        xo[tid * 4 + i] = o;
    }
#pragma unroll
    for (int off = 32; off > 0; off >>= 1) s += __shfl_down(s, off, 64);
    __shared__ float wsum[4];
    if ((tid & 63) == 0) wsum[tid >> 6] = s;
    __syncthreads();
    if (tid == 0) rowsum[row] = wsum[0] + wsum[1] + wsum[2] + wsum[3];
}

// ---------------- prep_w: int32 (0..255) -> bf16 (exact) ----------------
__global__ __launch_bounds__(256) void prep_w_kernel(
    const int* __restrict__ wq, u16* __restrict__ wb) {
    const size_t total8 = (size_t)OUT_F * IN_F / 8;
    size_t i = (size_t)blockIdx.x * blockDim.x + threadIdx.x;
    const size_t stride = (size_t)gridDim.x * blockDim.x;
    const int4* p = reinterpret_cast<const int4*>(wq);
    u16x8* o = reinterpret_cast<u16x8*>(wb);
    for (; i < total8; i += stride) {
        int4 a = p[i * 2];
        int4 b = p[i * 2 + 1];
        u16x8 v;
        v[0] = f2bf((float)a.x); v[1] = f2bf((float)a.y);
        v[2] = f2bf((float)a.z); v[3] = f2bf((float)a.w);
        v[4] = f2bf((float)b.x); v[5] = f2bf((float)b.y);
        v[6] = f2bf((float)b.z); v[7] = f2bf((float)b.w);
        o[i] = v;
    }
}

// ---------------- qgemm: 256x128 tile, BK=32, 2 blocks/CU, counted vmcnt -------
// C[t,o] = scale[o] * (sum_k Xb[t,k]*Wb[o,k] - zero[o]*rowsum[t]) + bias[o]
//
// LDS: A[2] double-buffer (16KB each), B[4] quad-buffer (8KB each) = 64KB total
// -> 2 blocks/CU (LDS 128/160KB, regs <=128/lane via launch_bounds(512,4)).
// Rows are 64B (32 bf16); XOR swizzle: 16B-slot ^= (row&3). Stage pre-swizzles
// the GLOBAL source (gload_lds writes linearly), reads apply the same XOR.
// Bank math: read start-banks = 16*(l15&1) + 4*(kq^(l15&3)) -> 8 uniform
// start positions x 8 lanes = minimum cycles, conflict-free.
//
// Per 2-tile iteration (tiles t -> Abuf0/Bbuf[t&3], t+1 -> Abuf1/Bbuf[(t+1)&3]),
// 4 phases, 8 MFMA each:
//   P1: ds A(t)+B(t,nh0); stage B(t+2);          MFMA(nh0)
//   P2: ds B(t,nh1);      stage A(t+2) (2 ld);   MFMA(nh1)  VM(3)
//   P3: ds A(t+1)+B(t+1,nh0); stage B(t+3);      MFMA(nh0)
//   P4: ds B(t+1,nh1);    stage A(t+3) (2 ld);   MFMA(nh1)  VM(3)
// Invariant: 3 loads outstanding at iteration boundary = {A(t+1)x2, B(t+1)};
// each VM(3) retires exactly one tile's regions. Never drains to 0 in-loop.

#define LDA(P)                                                                    \
    _Pragma("unroll") for (int m = 0; m < 4; ++m)                                 \
        af[m] = *(const bf16x8*)((const char*)&AS[P][0] +                         \
            ((wr * 64 + m * 16 + l15) * 64 + ((kq ^ (l15 & 3)) << 4)));

#define LDB(P, NH)                                                                \
    _Pragma("unroll") for (int n = 0; n < 2; ++n)                                 \
        bfr[n] = *(const bf16x8*)((const char*)&BS[P][0] +                        \
            ((wc * 64 + ((NH) * 2 + n) * 16 + l15) * 64 +                         \
             ((kq ^ (l15 & 3)) << 4)));

#define MFMA_H(NH)                                                                \
    __builtin_amdgcn_s_setprio(1);                                                \
    _Pragma("unroll") for (int m = 0; m < 4; ++m)                                 \
    _Pragma("unroll") for (int n = 0; n < 2; ++n)                                 \
        acc[m][(NH) * 2 + n] = __builtin_amdgcn_mfma_f32_16x16x32_bf16(           \
            af[m], bfr[n], acc[m][(NH) * 2 + n], 0, 0, 0);                        \
    __builtin_amdgcn_s_setprio(0);

// A tile = 16 chunks of 1KB; wave w stages chunks 2w, 2w+1 (rows 32w+16j..+16)
#define STAGE_A(P, KT)                                                            \
    _Pragma("unroll") for (int j = 0; j < 2; ++j) {                               \
        const u16* g_ = Abase + (size_t)(w * 32 + j * 16 + (lane >> 2)) * IN_F +  \
                        (KT) * BK + sa8;                                          \
        GLOAD_LDS16(g_, (char*)&AS[P][0] + (w * 2 + j) * 1024);                   \
    }

// B tile = 8 chunks of 1KB; wave w stages chunk w (rows 16w..16w+16)
#define STAGE_B(P, KT) {                                                          \
        const u16* g_ = Bbase + (size_t)(w * 16 + (lane >> 2)) * IN_F +           \
                        (KT) * BK + sa8;                                          \
        GLOAD_LDS16(g_, (char*)&BS[P][0] + w * 1024);                             \
    }

__global__ __launch_bounds__(512, 4) void qgemm_kernel(
    const u16* __restrict__ Xb, const u16* __restrict__ Wb,
    const float* __restrict__ rowsum, const float* __restrict__ scale,
    const float* __restrict__ zero, const float* __restrict__ bias,
    float* __restrict__ out) {
    __shared__ u16 AS[2][BM * BK];  // 2 x 16KB
    __shared__ u16 BS[4][BN * BK];  // 4 x 8KB

    // bijective XCD swizzle (grid = 1376 = 8 * 172); mt-major: blocks within an
    // XCD share the A panel (L2-hot), B panels stream from L3.
    int bid = blockIdx.x;
    bid = (bid & 7) * (MT * NT / 8) + (bid >> 3);
    const int mt = bid / NT;
    const int nt = bid % NT;

    const int tid  = threadIdx.x;
    const int w    = tid >> 6;        // wave 0..7
    const int lane = tid & 63;
    const int wr   = w >> 1;          // wave row quarter 0..3 (64 rows each)
    const int wc   = w & 1;           // wave col half 0..1 (64 cols each)
    const int l15  = lane & 15;
    const int kq   = lane >> 4;       // 0..3 (8-elem K slot)
    // stage source swizzle: slot = (lane&3) ^ (row&3), row&3 == (lane>>2)&3
    const int sa8  = (((lane & 3) ^ ((lane >> 2) & 3)) << 3);  // in u16 units

    const u16* Abase = Xb + (size_t)mt * BM * IN_F;
    const u16* Bbase = Wb + (size_t)nt * BN * IN_F;

    bf16x8 af[4];
    bf16x8 bfr[2];
    f32x4 acc[4][4];
    const f32x4 zf = {0.f, 0.f, 0.f, 0.f};
#pragma unroll
    for (int m = 0; m < 4; ++m)
#pragma unroll
        for (int n = 0; n < 4; ++n) acc[m][n] = zf;

    // ---- prologue: A(0)x2, B(0), A(1)x2, B(1); retire tile-0 regions ----
    STAGE_A(0, 0);
    STAGE_B(0, 0);
    STAGE_A(1, 1);
    STAGE_B(1, 1);
    VM(3);   // retires A(0)x2 + B(0); leaves {A(1)x2, B(1)}
    BAR();

    // ---- steady loop: 63 iterations, tiles 0..125 ----
    for (int i = 0; i < 63; ++i) {
        const int t = 2 * i;
        // P1: tile t, n-half 0
        LDA(0);
        LDB(t & 3, 0);
        STAGE_B((t + 2) & 3, t + 2);
        BAR();
        MFMA_H(0);
        BAR();
        // P2: tile t, n-half 1
        LDB(t & 3, 1);
        STAGE_A(0, t + 2);
        BAR();
        MFMA_H(1);
        VM(3);   // retires {A(t+1)x2, B(t+1)} for P3
        BAR();
        // P3: tile t+1, n-half 0
        LDA(1);
        LDB((t + 1) & 3, 0);
        STAGE_B((t + 3) & 3, t + 3);
        BAR();
        MFMA_H(0);
        BAR();
        // P4: tile t+1, n-half 1
        LDB((t + 1) & 3, 1);
        STAGE_A(1, t + 3);
        BAR();
        MFMA_H(1);
        VM(3);   // retires {A(t+2)x2, B(t+2)} for next P1
        BAR();
    }

    // ---- peeled final iteration: tiles 126 (bufs A0/B2), 127 (A1/B3) ----
    LDA(0); LDB(2, 0);
    BAR();
    MFMA_H(0);
    BAR();
    LDB(2, 1);
    BAR();
    MFMA_H(1);
    VM(0);   // drain: A(127)x2 + B(127)
    BAR();
    LDA(1); LDB(3, 0);
    BAR();
    MFMA_H(0);
    BAR();
    LDB(3, 1);
    BAR();
    MFMA_H(1);

    // ---- epilogue: C/D layout col = lane&15, row = (lane>>4)*4 + j ----
    const int rowt = mt * BM + wr * 64;
    const int colt = nt * BN + wc * 64;

    float rs[4][4];
#pragma unroll
    for (int m = 0; m < 4; ++m)
#pragma unroll
        for (int j = 0; j < 4; ++j)
            rs[m][j] = rowsum[rowt + m * 16 + kq * 4 + j];

#pragma unroll
    for (int n = 0; n < 4; ++n) {
        const int col = colt + n * 16 + l15;
        const float sc = scale[col];
        const float zp = zero[col];
        const float bs = bias[col];
#pragma unroll
        for (int m = 0; m < 4; ++m) {
            const int rb = rowt + m * 16 + kq * 4;
#pragma unroll
            for (int j = 0; j < 4; ++j) {
                out[(size_t)(rb + j) * OUT_F + col] =
                    sc * (acc[m][n][j] - zp * rs[m][j]) + bs;
            }
        }
    }
}

extern "C" void kernel_launch(void* const* d_in, const int* in_sizes, int n_in,
                              void* d_out, int out_size, void* d_ws, size_t ws_size,
                              hipStream_t stream) {
    const float* x     = (const float*)d_in[0];
    const int*   wq    = (const int*)d_in[1];
    const float* scale = (const float*)d_in[2];
    const float* zero  = (const float*)d_in[3];
    const float* bias  = (const float*)d_in[4];
    float* out = (float*)d_out;

    // workspace layout: Wb (90.2 MB) | Xb (33.6 MB) | rowsum (16 KB)
    char* ws = (char*)d_ws;
    u16* Wb = (u16*)ws;
    u16* Xb = (u16*)(ws + (size_t)OUT_F * IN_F * 2);
    float* rowsum = (float*)(ws + (size_t)OUT_F * IN_F * 2 + (size_t)TOKENS * IN_F * 2);

    prep_w_kernel<<<2048, 256, 0, stream>>>(wq, Wb);
    prep_x_kernel<<<TOKENS, 256, 0, stream>>>(x, Xb, rowsum);
    qgemm_kernel<<<MT * NT, 512, 0, stream>>>(Xb, Wb, rowsum, scale, zero, bias, out);
}

// Round 4
// 441.510 us; speedup vs baseline: 1.0012x; 1.0012x over previous
//
#include <hip/hip_runtime.h>

typedef unsigned short u16;
typedef unsigned int   u32;
typedef unsigned long long u64;

typedef __bf16 bf16x8 __attribute__((ext_vector_type(8)));
typedef float  f32x4  __attribute__((ext_vector_type(4)));
typedef u16    u16x4  __attribute__((ext_vector_type(4)));
typedef u16    u16x8  __attribute__((ext_vector_type(8)));

#define IN_F   4096
#define OUT_F  11008
#define TOKENS 4096

#define BM 256
#define BN 128
#define BK 32
#define MT (TOKENS / BM)   // 16
#define NT (OUT_F / BN)    // 86
#define KTILES (IN_F / BK) // 128

// f32 -> bf16 round-to-nearest-even (exact for integers 0..255)
__device__ __forceinline__ u16 f2bf(float f) {
    u32 u = __float_as_uint(f);
    return (u16)((u + 0x7FFFu + ((u >> 16) & 1u)) >> 16);
}

// direct global->LDS async copy, 16B per lane; LDS dest = wave-uniform base + lane*16
#define GLOAD_LDS16(g, l)                                                        \
    __builtin_amdgcn_global_load_lds(                                            \
        (const __attribute__((address_space(1))) u32*)(u64)(g),                  \
        (__attribute__((address_space(3))) u32*)(u64)(l), 16, 0, 0)

#define BAR() __builtin_amdgcn_s_barrier()
#define VM(N) asm volatile("s_waitcnt vmcnt(" #N ")" ::: "memory")

// ---------------- prep_x: f32 -> bf16, plus per-row f32 sum ----------------
__global__ __launch_bounds__(256) void prep_x_kernel(
    const float* __restrict__ x, u16* __restrict__ xb, float* __restrict__ rowsum) {
    const int row = blockIdx.x;
    const int tid = threadIdx.x;
    const float4* xr = reinterpret_cast<const float4*>(x + (size_t)row * IN_F);
    u16x4* xo = reinterpret_cast<u16x4*>(xb + (size_t)row * IN_F);
    float s = 0.f;
#pragma unroll
    for (int i = 0; i < 4; ++i) {
        float4 v = xr[tid * 4 + i];
        s += v.x + v.y + v.z + v.w;
        u16x4 o;
        o[0] = f2bf(v.x); o[1] = f2bf(v.y); o[2] = f2bf(v.z); o[3] = f2bf(v.w);
        xo[tid * 4 + i] = o;
    }
#pragma unroll
    for (int off = 32; off > 0; off >>= 1) s += __shfl_down(s, off, 64);
    __shared__ float wsum[4];
    if ((tid & 63) == 0) wsum[tid >> 6] = s;
    __syncthreads();
    if (tid == 0) rowsum[row] = wsum[0] + wsum[1] + wsum[2] + wsum[3];
}

// ---------------- prep_w: int32 (0..255) -> bf16 (exact) ----------------
__global__ __launch_bounds__(256) void prep_w_kernel(
    const int* __restrict__ wq, u16* __restrict__ wb) {
    const size_t total8 = (size_t)OUT_F * IN_F / 8;
    size_t i = (size_t)blockIdx.x * blockDim.x + threadIdx.x;
    const size_t stride = (size_t)gridDim.x * blockDim.x;
    const int4* p = reinterpret_cast<const int4*>(wq);
    u16x8* o = reinterpret_cast<u16x8*>(wb);
    for (; i < total8; i += stride) {
        int4 a = p[i * 2];
        int4 b = p[i * 2 + 1];
        u16x8 v;
        v[0] = f2bf((float)a.x); v[1] = f2bf((float)a.y);
        v[2] = f2bf((float)a.z); v[3] = f2bf((float)a.w);
        v[4] = f2bf((float)b.x); v[5] = f2bf((float)b.y);
        v[6] = f2bf((float)b.z); v[7] = f2bf((float)b.w);
        o[i] = v;
    }
}

// ---------------- qgemm: 256x128 tile, BK=32, 2 blocks/CU, counted vmcnt -------
// C[t,o] = scale[o] * (sum_k Xb[t,k]*Wb[o,k] - zero[o]*rowsum[t]) + bias[o]
//
// LDS: A[2] double-buffer (16KB each), B[4] quad-buffer (8KB each) = 64KB total
// -> 2 blocks/CU. Rows are 64B (32 bf16) = half a bank sweep; row parity is
// position-bit 0, so the XOR swizzle must inject row bits 1..2 (NOT 0..1):
//   16B-slot ^= (row>>1)&3
// Read position over 8 consecutive lanes (l15=0..7):
//   (parity, slot) = (l15&1, kq^((l15>>1)&3)) -> all 8 positions covered
// (round-3's slot^=(row&3) had period 4 -> 2-way conflict, 4.5e7 counted).
// Stage pre-swizzles the GLOBAL source (gload_lds writes linearly; rule 21):
// lane writes LDS slot lane&3 of chunk-row lane>>2, so it must fetch global
// slot (lane&3)^(((lane>>2)>>1)&3) = (lane&3)^((lane>>3)&3).
//
// Per 2-tile iteration (tiles t -> Abuf0/Bbuf[t&3], t+1 -> Abuf1/Bbuf[(t+1)&3]),
// 4 phases, 8 MFMA each; VM(3) twice per iteration, never 0 in-loop.

#define LDA(P)                                                                    \
    _Pragma("unroll") for (int m = 0; m < 4; ++m)                                 \
        af[m] = *(const bf16x8*)((const char*)&AS[P][0] +                         \
            ((wr * 64 + m * 16 + l15) * 64 + ((kq ^ ((l15 >> 1) & 3)) << 4)));

#define LDB(P, NH)                                                                \
    _Pragma("unroll") for (int n = 0; n < 2; ++n)                                 \
        bfr[n] = *(const bf16x8*)((const char*)&BS[P][0] +                        \
            ((wc * 64 + ((NH) * 2 + n) * 16 + l15) * 64 +                         \
             ((kq ^ ((l15 >> 1) & 3)) << 4)));

#define MFMA_H(NH)                                                                \
    __builtin_amdgcn_s_setprio(1);                                                \
    _Pragma("unroll") for (int m = 0; m < 4; ++m)                                 \
    _Pragma("unroll") for (int n = 0; n < 2; ++n)                                 \
        acc[m][(NH) * 2 + n] = __builtin_amdgcn_mfma_f32_16x16x32_bf16(           \
            af[m], bfr[n], acc[m][(NH) * 2 + n], 0, 0, 0);                        \
    __builtin_amdgcn_s_setprio(0);

// A tile = 16 chunks of 1KB; wave w stages chunks 2w, 2w+1 (rows 32w+16j..+16)
#define STAGE_A(P, KT)                                                            \
    _Pragma("unroll") for (int j = 0; j < 2; ++j) {                               \
        const u16* g_ = Abase + (size_t)(w * 32 + j * 16 + (lane >> 2)) * IN_F +  \
                        (KT) * BK + sa8;                                          \
        GLOAD_LDS16(g_, (char*)&AS[P][0] + (w * 2 + j) * 1024);                   \
    }

// B tile = 8 chunks of 1KB; wave w stages chunk w (rows 16w..16w+16)
#define STAGE_B(P, KT) {                                                          \
        const u16* g_ = Bbase + (size_t)(w * 16 + (lane >> 2)) * IN_F +           \
                        (KT) * BK + sa8;                                          \
        GLOAD_LDS16(g_, (char*)&BS[P][0] + w * 1024);                             \
    }

__global__ __launch_bounds__(512, 4) void qgemm_kernel(
    const u16* __restrict__ Xb, const u16* __restrict__ Wb,
    const float* __restrict__ rowsum, const float* __restrict__ scale,
    const float* __restrict__ zero, const float* __restrict__ bias,
    float* __restrict__ out) {
    __shared__ u16 AS[2][BM * BK];  // 2 x 16KB
    __shared__ u16 BS[4][BN * BK];  // 4 x 8KB

    // bijective XCD swizzle (grid = 1376 = 8 * 172); mt-major: blocks within an
    // XCD share the A panel (L2-hot), B panels stream from L3.
    int bid = blockIdx.x;
    bid = (bid & 7) * (MT * NT / 8) + (bid >> 3);
    const int mt = bid / NT;
    const int nt = bid % NT;

    const int tid  = threadIdx.x;
    const int w    = tid >> 6;        // wave 0..7
    const int lane = tid & 63;
    const int wr   = w >> 1;          // wave row quarter 0..3 (64 rows each)
    const int wc   = w & 1;           // wave col half 0..1 (64 cols each)
    const int l15  = lane & 15;
    const int kq   = lane >> 4;       // 0..3 (8-elem K slot)
    // stage source swizzle: LDS slot lane&3 at chunk-row lane>>2 must hold
    // global slot (lane&3) ^ ((row>>1)&3) = (lane&3) ^ ((lane>>3)&3)
    const int sa8  = (((lane & 3) ^ ((lane >> 3) & 3)) << 3);  // in u16 units

    const u16* Abase = Xb + (size_t)mt * BM * IN_F;
    const u16* Bbase = Wb + (size_t)nt * BN * IN_F;

    bf16x8 af[4];
    bf16x8 bfr[2];
    f32x4 acc[4][4];
    const f32x4 zf = {0.f, 0.f, 0.f, 0.f};
#pragma unroll
    for (int m = 0; m < 4; ++m)
#pragma unroll
        for (int n = 0; n < 4; ++n) acc[m][n] = zf;

    // ---- prologue: A(0)x2, B(0), A(1)x2, B(1); retire tile-0 regions ----
    STAGE_A(0, 0);
    STAGE_B(0, 0);
    STAGE_A(1, 1);
    STAGE_B(1, 1);
    VM(3);   // retires A(0)x2 + B(0); leaves {A(1)x2, B(1)}
    BAR();

    // ---- steady loop: 63 iterations, tiles 0..125 ----
    for (int i = 0; i < 63; ++i) {
        const int t = 2 * i;
        // P1: tile t, n-half 0
        LDA(0);
        LDB(t & 3, 0);
        STAGE_B((t + 2) & 3, t + 2);
        BAR();
        MFMA_H(0);
        BAR();
        // P2: tile t, n-half 1
        LDB(t & 3, 1);
        STAGE_A(0, t + 2);
        BAR();
        MFMA_H(1);
        VM(3);   // retires {A(t+1)x2, B(t+1)} for P3
        BAR();
        // P3: tile t+1, n-half 0
        LDA(1);
        LDB((t + 1) & 3, 0);
        STAGE_B((t + 3) & 3, t + 3);
        BAR();
        MFMA_H(0);
        BAR();
        // P4: tile t+1, n-half 1
        LDB((t + 1) & 3, 1);
        STAGE_A(1, t + 3);
        BAR();
        MFMA_H(1);
        VM(3);   // retires {A(t+2)x2, B(t+2)} for next P1
        BAR();
    }

    // ---- peeled final iteration: tiles 126 (bufs A0/B2), 127 (A1/B3) ----
    LDA(0); LDB(2, 0);
    BAR();
    MFMA_H(0);
    BAR();
    LDB(2, 1);
    BAR();
    MFMA_H(1);
    VM(0);   // drain: A(127)x2 + B(127)
    BAR();
    LDA(1); LDB(3, 0);
    BAR();
    MFMA_H(0);
    BAR();
    LDB(3, 1);
    BAR();
    MFMA_H(1);

    // ---- epilogue: C/D layout col = lane&15, row = (lane>>4)*4 + j ----
    const int rowt = mt * BM + wr * 64;
    const int colt = nt * BN + wc * 64;

    float rs[4][4];
#pragma unroll
    for (int m = 0; m < 4; ++m)
#pragma unroll
        for (int j = 0; j < 4; ++j)
            rs[m][j] = rowsum[rowt + m * 16 + kq * 4 + j];

#pragma unroll
    for (int n = 0; n < 4; ++n) {
        const int col = colt + n * 16 + l15;
        const float sc = scale[col];
        const float zp = zero[col];
        const float bs = bias[col];
#pragma unroll
        for (int m = 0; m < 4; ++m) {
            const int rb = rowt + m * 16 + kq * 4;
#pragma unroll
            for (int j = 0; j < 4; ++j) {
                out[(size_t)(rb + j) * OUT_F + col] =
                    sc * (acc[m][n][j] - zp * rs[m][j]) + bs;
            }
        }
    }
}

extern "C" void kernel_launch(void* const* d_in, const int* in_sizes, int n_in,
                              void* d_out, int out_size, void* d_ws, size_t ws_size,
                              hipStream_t stream) {
    const float* x     = (const float*)d_in[0];
    const int*   wq    = (const int*)d_in[1];
    const float* scale = (const float*)d_in[2];
    const float* zero  = (const float*)d_in[3];
    const float* bias  = (const float*)d_in[4];
    float* out = (float*)d_out;

    // workspace layout: Wb (90.2 MB) | Xb (33.6 MB) | rowsum (16 KB)
    char* ws = (char*)d_ws;
    u16* Wb = (u16*)ws;
    u16* Xb = (u16*)(ws + (size_t)OUT_F * IN_F * 2);
    float* rowsum = (float*)(ws + (size_t)OUT_F * IN_F * 2 + (size_t)TOKENS * IN_F * 2);

    prep_w_kernel<<<2048, 256, 0, stream>>>(wq, Wb);
    prep_x_kernel<<<TOKENS, 256, 0, stream>>>(x, Xb, rowsum);
    qgemm_kernel<<<MT * NT, 512, 0, stream>>>(Xb, Wb, rowsum, scale, zero, bias, out);
}